// Round 8
// baseline (969.797 us; speedup 1.0000x reference)
//
#include <hip/hip_runtime.h>
#include <hip/hip_bf16.h>

// Node_EncodingBlock on MI355X. Inputs fp32, output fp32.
// R8: MEASUREMENT ROUND. Real path identical to R7 (validated). Three probe
// kernels re-run exact copies of the hot kernels into scratch, repeated so
// they exceed the harness's 39.5us fill dispatches and appear in top-5:
//   T_attn = dur(p_attn)/5, T_ffn = dur(p_ffn)/8, T_final = dur(p_final)/12.

#define BN_EPS 1e-5f
// ws layout (float offsets)
#define WS_X1    256000     // [2000][128]
#define WS_X2    512000     // [2000][128]
#define WS_PERM  768000     // [4][128] int
#define WS_U     768512
#define WS_C0    768640
#define WS_SUM1  768768
#define WS_SQ1   768896
#define WS_SUM2  769024
#define WS_SQ2   769152
#define WS_MLPU  769280     // [8][16] u_s
#define WS_MLPR  769408     // [8][16] r_s
#define WS_MLPAB 769536     // [8][2]  A,B
// probe scratch (never read; d_out untouched by probes)
#define P_X1     1048576
#define P_SUMA   1348576
#define P_X2     1448576
#define P_SUMF   1748576
#define P_OUT    1848576
#define REP_ATTN 5
#define REP_FFN  8
#define REP_FIN  12

// ---- init: argsort perm, demand vectors, BN zeros, MLP abs-form params ----
__global__ __launch_bounds__(128) void k_init(const float* __restrict__ rnd,
                                              const float* __restrict__ Wd,
                                              const float* __restrict__ bd,
                                              const float* __restrict__ Wn,
                                              const float* __restrict__ bnn,
                                              const float* __restrict__ mix1w,
                                              const float* __restrict__ mix1b,
                                              const float* __restrict__ mix2w,
                                              const float* __restrict__ mix2b,
                                              float* __restrict__ ws) {
  const int t = threadIdx.x;
  const int b = blockIdx.x;
  if (b < 4) {
    __shared__ float v[128];
    __shared__ int ps[128];
    float vt = rnd[b * 128 + t];
    v[t] = vt;
    __syncthreads();
    int rank = 0;
    for (int j = 0; j < 128; ++j) {
      float vj = v[j];
      rank += (vj < vt) || (vj == vt && j < t);
    }
    ps[rank] = t;
    __syncthreads();
    ((int*)(ws + WS_PERM))[b * 128 + t] = ps[t];
  } else if (b == 4) {
    float u = 0.f, c0 = 0.f;
#pragma unroll 8
    for (int e = 0; e < 128; ++e) {
      float wn = Wn[(128 + e) * 128 + t];
      u  = fmaf(Wd[e], wn, u);
      c0 = fmaf(bd[e], wn, c0);
    }
    ws[WS_U + t]  = u;
    ws[WS_C0 + t] = c0 + bnn[t];
    ws[WS_SUM1 + t] = 0.f; ws[WS_SQ1 + t] = 0.f;
    ws[WS_SUM2 + t] = 0.f; ws[WS_SQ2 + t] = 0.f;
  } else {
    // abs-form MLP params: g(c) = A c + B + sum u_s |c - r_s|
    const int h = t >> 4, s = t & 15;
    float w1  = mix1w[h * 32 + 16 + s];
    float b1v = mix1b[h * 16 + s];
    float w2  = mix2w[h * 16 + s];
    bool tiny = fabsf(w1) < 1e-20f;
    float us = tiny ? 0.f : 0.5f * w2 * fabsf(w1);
    float rs = tiny ? 0.f : -b1v / w1;
    float Ap = 0.5f * w2 * w1;
    float Bp = 0.5f * w2 * b1v + (tiny ? 0.5f * w2 * fabsf(b1v) : 0.f);
    ws[WS_MLPU + h * 16 + s] = us;
    ws[WS_MLPR + h * 16 + s] = rs;
#pragma unroll
    for (int off = 1; off < 16; off <<= 1) {
      Ap += __shfl_xor(Ap, off);
      Bp += __shfl_xor(Bp, off);
    }
    if (s == 0) {
      ws[WS_MLPAB + h * 2]     = Ap;
      ws[WS_MLPAB + h * 2 + 1] = Bp + mix2b[h];
    }
  }
}

#define GEMM_BATCH8(WPTR, LDW, KIDX, ACT2D, ACC)                        \
  {                                                                     \
    float4 w[8];                                                        \
    _Pragma("unroll")                                                   \
    for (int u = 0; u < 8; ++u)                                         \
      w[u] = *(const float4*)((WPTR) + (size_t)((KIDX) + u) * (LDW));   \
    _Pragma("unroll")                                                   \
    for (int u = 0; u < 8; ++u) {                                       \
      _Pragma("unroll")                                                 \
      for (int r = 0; r < 4; ++r) {                                     \
        float a = ACT2D[r][u];                                          \
        ACC[r][0] = fmaf(a, w[u].x, ACC[r][0]);                         \
        ACC[r][1] = fmaf(a, w[u].y, ACC[r][1]);                         \
        ACC[r][2] = fmaf(a, w[u].z, ACC[r][2]);                         \
        ACC[r][3] = fmaf(a, w[u].w, ACC[r][3]);                         \
      }                                                                 \
    }                                                                   \
  }

#define LOAD_ACT8(SRC2D, KIDX, ACT2D)                                   \
  {                                                                     \
    _Pragma("unroll")                                                   \
    for (int r = 0; r < 4; ++r) {                                       \
      float4 x = *(const float4*)&SRC2D[r][(KIDX)];                     \
      float4 y = *(const float4*)&SRC2D[r][(KIDX) + 4];                 \
      ACT2D[r][0] = x.x; ACT2D[r][1] = x.y; ACT2D[r][2] = x.z;          \
      ACT2D[r][3] = x.w; ACT2D[r][4] = y.x; ACT2D[r][5] = y.y;          \
      ACT2D[r][6] = y.z; ACT2D[r][7] = y.w;                             \
    }                                                                   \
  }

#define GEMM_BATCH8_R2(WPTR, LDW, KIDX, ACT2D, ACC)                     \
  {                                                                     \
    float4 w[8];                                                        \
    _Pragma("unroll")                                                   \
    for (int u = 0; u < 8; ++u)                                         \
      w[u] = *(const float4*)((WPTR) + (size_t)((KIDX) + u) * (LDW));   \
    _Pragma("unroll")                                                   \
    for (int u = 0; u < 8; ++u) {                                       \
      _Pragma("unroll")                                                 \
      for (int r = 0; r < 2; ++r) {                                     \
        float a = ACT2D[r][u];                                          \
        ACC[r][0] = fmaf(a, w[u].x, ACC[r][0]);                         \
        ACC[r][1] = fmaf(a, w[u].y, ACC[r][1]);                         \
        ACC[r][2] = fmaf(a, w[u].z, ACC[r][2]);                         \
        ACC[r][3] = fmaf(a, w[u].w, ACC[r][3]);                         \
      }                                                                 \
    }                                                                   \
  }

// ---- attn+mho body (REPS=1 -> real kernel writing WS_X1/WS_SUM1) ---------
#define ATTN_BODY(REPS, XBASE, SBASE, QBASE)                                  \
  __shared__ float scost[4][512];                                             \
  __shared__ float aw[32][132];                                               \
  __shared__ float soc[4][132];                                               \
  __shared__ float sP[8][512];                                                \
  __shared__ int   sperm[128];                                                \
  __shared__ float sS[512], sQ[512];                                          \
  const int t = threadIdx.x;                                                  \
  const int lane = t & 63;                                                    \
  const int row0 = blockIdx.x * 4;                                            \
  const int b = row0 / 500;                                                   \
  for (int it = 0; it < (REPS); ++it) {                                       \
    __syncthreads();                                                          \
    if (t < 500) {                                                            \
      int rr = t / 125, i4 = t - rr * 125;                                    \
      *(float4*)&scost[rr][i4 * 4] =                                          \
          *(const float4*)(cost + (size_t)(row0 + rr) * 500 + i4 * 4);        \
    } else {                                                                  \
      int idx = t - 500;                                                      \
      int rr = idx & 3, m0 = 500 + (idx >> 2) * 4;                            \
      *(float4*)&scost[rr][m0] = float4{0.f, 0.f, 0.f, 0.f};                  \
    }                                                                         \
    if (t < 128) sperm[t] = ((const int*)(ws + WS_PERM))[b * 128 + t];        \
    __syncthreads();                                                          \
    {                                                                         \
      const int wid = t >> 6;                                                 \
      const int r  = wid & 3;                                                 \
      const int h0 = (wid >> 2) * 4;                                          \
      float cv[8];                                                            \
      _Pragma("unroll")                                                       \
      for (int ii = 0; ii < 8; ++ii) cv[ii] = scost[r][ii * 64 + lane];       \
      for (int h = h0; h < h0 + 4; ++h) {                                     \
        float4 uq[4], rq[4];                                                  \
        _Pragma("unroll")                                                     \
        for (int q = 0; q < 4; ++q) {                                         \
          uq[q] = *(const float4*)(ws + WS_MLPU + h * 16 + q * 4);            \
          rq[q] = *(const float4*)(ws + WS_MLPR + h * 16 + q * 4);            \
        }                                                                     \
        const float A  = ws[WS_MLPAB + h * 2];                                \
        const float Bc = ws[WS_MLPAB + h * 2 + 1];                            \
        float wsum = 0.f, a0 = 0.f, a1 = 0.f;                                 \
        _Pragma("unroll")                                                     \
        for (int ii = 0; ii < 8; ++ii) {                                      \
          float c = cv[ii];                                                   \
          float s = fmaf(c, A, Bc);                                           \
          _Pragma("unroll")                                                   \
          for (int q = 0; q < 4; ++q) {                                       \
            s = fmaf(fabsf(c - rq[q].x), uq[q].x, s);                         \
            s = fmaf(fabsf(c - rq[q].y), uq[q].y, s);                         \
            s = fmaf(fabsf(c - rq[q].z), uq[q].z, s);                         \
            s = fmaf(fabsf(c - rq[q].w), uq[q].w, s);                         \
          }                                                                   \
          if (ii == 7) s = (lane < 52) ? s : -1e30f;                          \
          float e = __expf(s);                                                \
          wsum += e;                                                          \
          if (ii & 1) a1 += e; else a0 += e;                                  \
        }                                                                     \
        _Pragma("unroll")                                                     \
        for (int off = 32; off; off >>= 1) wsum += __shfl_xor(wsum, off);     \
        float inv = 1.f / wsum;                                               \
        aw[r * 8 + h][lane]      = a0 * inv;                                  \
        aw[r * 8 + h][64 + lane] = a1 * inv;                                  \
      }                                                                       \
    }                                                                         \
    __syncthreads();                                                          \
    {                                                                         \
      const int c  = t & 127;                                                 \
      const int jh = t >> 7;                                                  \
      const int h  = c >> 4;                                                  \
      float acc4[4] = {0.f, 0.f, 0.f, 0.f};                                   \
      for (int jb = jh * 32; jb < jh * 32 + 32; jb += 8) {                    \
        int rows[8];                                                          \
        _Pragma("unroll")                                                     \
        for (int u = 0; u < 8; ++u) rows[u] = sperm[jb + u];                  \
        float wv8[8];                                                         \
        _Pragma("unroll")                                                     \
        for (int u = 0; u < 8; ++u) wv8[u] = Wv[(size_t)rows[u] * 128 + c];   \
        _Pragma("unroll")                                                     \
        for (int r = 0; r < 4; ++r) {                                         \
          float4 aa = *(const float4*)&aw[r * 8 + h][jb];                     \
          float4 ab = *(const float4*)&aw[r * 8 + h][jb + 4];                 \
          acc4[r] = fmaf(aa.x, wv8[0], acc4[r]);                              \
          acc4[r] = fmaf(aa.y, wv8[1], acc4[r]);                              \
          acc4[r] = fmaf(aa.z, wv8[2], acc4[r]);                              \
          acc4[r] = fmaf(aa.w, wv8[3], acc4[r]);                              \
          acc4[r] = fmaf(ab.x, wv8[4], acc4[r]);                              \
          acc4[r] = fmaf(ab.y, wv8[5], acc4[r]);                              \
          acc4[r] = fmaf(ab.z, wv8[6], acc4[r]);                              \
          acc4[r] = fmaf(ab.w, wv8[7], acc4[r]);                              \
        }                                                                     \
      }                                                                       \
      _Pragma("unroll")                                                       \
      for (int r = 0; r < 4; ++r) sP[jh][r * 128 + c] = acc4[r];              \
    }                                                                         \
    __syncthreads();                                                          \
    {                                                                         \
      int r = t >> 7, c = t & 127;                                            \
      soc[r][c] = sP[0][r * 128 + c] + sP[1][r * 128 + c] +                   \
                  sP[2][r * 128 + c] + sP[3][r * 128 + c];                    \
    }                                                                         \
    __syncthreads();                                                          \
    {                                                                         \
      const int cg  = (t & 31) * 4;                                           \
      const int seg = (t >> 5) & 7;                                           \
      const int rh  = t >> 8;                                                 \
      const int k0  = seg * 16;                                               \
      float acc[2][4] = {};                                                   \
      float av[2][8];                                                         \
      _Pragma("unroll")                                                       \
      for (int kb = 0; kb < 16; kb += 8) {                                    \
        _Pragma("unroll")                                                     \
        for (int r = 0; r < 2; ++r) {                                         \
          float4 x = *(const float4*)&soc[rh * 2 + r][k0 + kb];               \
          float4 y = *(const float4*)&soc[rh * 2 + r][k0 + kb + 4];           \
          av[r][0] = x.x; av[r][1] = x.y; av[r][2] = x.z; av[r][3] = x.w;     \
          av[r][4] = y.x; av[r][5] = y.y; av[r][6] = y.z; av[r][7] = y.w;     \
        }                                                                     \
        GEMM_BATCH8_R2(Wo + cg, 128, k0 + kb, av, acc);                       \
      }                                                                       \
      _Pragma("unroll")                                                       \
      for (int r = 0; r < 2; ++r)                                             \
        *(float4*)&sP[seg][(rh * 2 + r) * 128 + cg] = *(float4*)acc[r];       \
    }                                                                         \
    __syncthreads();                                                          \
    {                                                                         \
      int r = t >> 7, col = t & 127;                                          \
      float x = bo[col];                                                      \
      _Pragma("unroll")                                                       \
      for (int sg = 0; sg < 8; ++sg) x += sP[sg][r * 128 + col];              \
      ws[(XBASE) + (size_t)(row0 + r) * 128 + col] = x;                       \
      sS[t] = x; sQ[t] = x * x;                                               \
    }                                                                         \
    __syncthreads();                                                          \
    if (t < 128) {                                                            \
      atomicAdd(ws + (SBASE) + t, sS[t] + sS[t+128] + sS[t+256] + sS[t+384]); \
      atomicAdd(ws + (QBASE) + t, sQ[t] + sQ[t+128] + sQ[t+256] + sQ[t+384]); \
    }                                                                         \
  }

__global__ __launch_bounds__(512, 4) void k_attn_mho(const float* __restrict__ cost,
                                                     const float* __restrict__ Wv,
                                                     const float* __restrict__ Wo,
                                                     const float* __restrict__ bo,
                                                     float* __restrict__ ws) {
  ATTN_BODY(1, WS_X1, WS_SUM1, WS_SQ1)
}

__global__ __launch_bounds__(512, 4) void p_attn(const float* __restrict__ cost,
                                                 const float* __restrict__ Wv,
                                                 const float* __restrict__ Wo,
                                                 const float* __restrict__ bo,
                                                 float* __restrict__ ws) {
  ATTN_BODY(REP_ATTN, P_X1, P_SUMA, P_SUMA + 128)
}

// ---- ffn body -------------------------------------------------------------
#define FFN_BODY(REPS, X2BASE, SBASE, QBASE)                                  \
  __shared__ float o1[8][128];                                                \
  __shared__ float sY[8][512];                                                \
  __shared__ float sP[8][8][128];                                             \
  __shared__ float sc[128], sh[128];                                          \
  __shared__ float sS[512], sQ[512];                                          \
  const int t = threadIdx.x;                                                  \
  const int row0 = blockIdx.x * 8;                                            \
  for (int it = 0; it < (REPS); ++it) {                                       \
    __syncthreads();                                                          \
    if (t < 128) {                                                            \
      float m = ws[WS_SUM1 + t] * 5e-4f;                                      \
      float v = ws[WS_SQ1 + t] * 5e-4f - m * m;                               \
      float rs = rsqrtf(v + BN_EPS);                                          \
      float s = g1[t] * rs;                                                   \
      sc[t] = s;                                                              \
      sh[t] = bb1[t] - m * s;                                                 \
    }                                                                         \
    __syncthreads();                                                          \
    for (int i = t; i < 1024; i += 512) {                                     \
      int r = i >> 7, c = i & 127;                                            \
      o1[r][c] = ws[WS_X1 + (size_t)(row0 + r) * 128 + c] * sc[c] + sh[c];    \
    }                                                                         \
    __syncthreads();                                                          \
    {                                                                         \
      const int cg   = (t & 127) * 4;                                         \
      const int kseg = (t >> 7) & 1;                                          \
      const int rh   = t >> 8;                                                \
      const int kb0  = kseg * 64;                                             \
      float acc[4][4] = {};                                                   \
      float av[4][8];                                                         \
      _Pragma("unroll")                                                       \
      for (int k0 = 0; k0 < 64; k0 += 8) {                                    \
        LOAD_ACT8((o1 + rh * 4), kb0 + k0, av);                               \
        GEMM_BATCH8(W1 + cg, 512, kb0 + k0, av, acc);                         \
      }                                                                       \
      float* pf = &sP[0][0][0];                                               \
      if (kseg == 1) {                                                        \
        _Pragma("unroll")                                                     \
        for (int r = 0; r < 4; ++r)                                           \
          *(float4*)(pf + (size_t)(rh * 4 + r) * 512 + cg) = *(float4*)acc[r];\
      }                                                                       \
      __syncthreads();                                                        \
      if (kseg == 0) {                                                        \
        float4 bv = *(const float4*)(b1 + cg);                                \
        _Pragma("unroll")                                                     \
        for (int r = 0; r < 4; ++r) {                                         \
          float4 p = *(float4*)(pf + (size_t)(rh * 4 + r) * 512 + cg);        \
          float4 y = {fmaxf(acc[r][0] + p.x + bv.x, 0.f),                     \
                      fmaxf(acc[r][1] + p.y + bv.y, 0.f),                     \
                      fmaxf(acc[r][2] + p.z + bv.z, 0.f),                     \
                      fmaxf(acc[r][3] + p.w + bv.w, 0.f)};                    \
          *(float4*)&sY[rh * 4 + r][cg] = y;                                  \
        }                                                                     \
      }                                                                       \
    }                                                                         \
    __syncthreads();                                                          \
    {                                                                         \
      const int cg   = (t & 31) * 4;                                          \
      const int kseg = (t >> 5) & 7;                                          \
      const int rh   = t >> 8;                                                \
      const int k0   = kseg * 64;                                             \
      float acc[4][4] = {};                                                   \
      float av[4][8];                                                         \
      _Pragma("unroll")                                                       \
      for (int kb = 0; kb < 64; kb += 8) {                                    \
        LOAD_ACT8((sY + rh * 4), k0 + kb, av);                                \
        GEMM_BATCH8(W2 + cg, 128, k0 + kb, av, acc);                          \
      }                                                                       \
      _Pragma("unroll")                                                       \
      for (int r = 0; r < 4; ++r)                                             \
        *(float4*)&sP[kseg][rh * 4 + r][cg] = *(float4*)acc[r];               \
    }                                                                         \
    __syncthreads();                                                          \
    float s = 0.f, q = 0.f;                                                   \
    _Pragma("unroll")                                                         \
    for (int pass = 0; pass < 2; ++pass) {                                    \
      int idx = t + pass * 512;                                               \
      int col = idx & 127, r = idx >> 7;                                      \
      float x = b2[col] + o1[r][col];                                         \
      _Pragma("unroll")                                                       \
      for (int sg = 0; sg < 8; ++sg) x += sP[sg][r][col];                     \
      ws[(X2BASE) + (size_t)(row0 + r) * 128 + col] = x;                      \
      s += x; q = fmaf(x, x, q);                                              \
    }                                                                         \
    sS[t] = s; sQ[t] = q;                                                     \
    __syncthreads();                                                          \
    if (t < 128) {                                                            \
      atomicAdd(ws + (SBASE) + t, sS[t] + sS[t+128] + sS[t+256] + sS[t+384]); \
      atomicAdd(ws + (QBASE) + t, sQ[t] + sQ[t+128] + sQ[t+256] + sQ[t+384]); \
    }                                                                         \
  }

__global__ __launch_bounds__(512) void k_ffn(const float* __restrict__ W1,
                                             const float* __restrict__ b1,
                                             const float* __restrict__ g1,
                                             const float* __restrict__ bb1,
                                             const float* __restrict__ W2,
                                             const float* __restrict__ b2,
                                             float* __restrict__ ws) {
  FFN_BODY(1, WS_X2, WS_SUM2, WS_SQ2)
}

__global__ __launch_bounds__(512) void p_ffn(const float* __restrict__ W1,
                                             const float* __restrict__ b1,
                                             const float* __restrict__ g1,
                                             const float* __restrict__ bb1,
                                             const float* __restrict__ W2,
                                             const float* __restrict__ b2,
                                             float* __restrict__ ws) {
  FFN_BODY(REP_FFN, P_X2, P_SUMF, P_SUMF + 128)
}

// ---- final body -----------------------------------------------------------
#define FIN_BODY(REPS, OUTPTR)                                                \
  __shared__ float o3[4][132];                                                \
  __shared__ float sP[8][512];                                                \
  __shared__ float sc[128], sh[128];                                          \
  const int t = threadIdx.x;                                                  \
  const int row0 = blockIdx.x * 4;                                            \
  for (int it = 0; it < (REPS); ++it) {                                       \
    __syncthreads();                                                          \
    if (t < 128) {                                                            \
      float m = ws[WS_SUM2 + t] * 5e-4f;                                      \
      float v = ws[WS_SQ2 + t] * 5e-4f - m * m;                               \
      float rs = rsqrtf(v + BN_EPS);                                          \
      float s = g2[t] * rs;                                                   \
      sc[t] = s;                                                              \
      sh[t] = bb2[t] - m * s;                                                 \
    }                                                                         \
    __syncthreads();                                                          \
    for (int i = t; i < 512; i += 256) {                                      \
      int r = i >> 7, c = i & 127;                                            \
      o3[r][c] = ws[WS_X2 + (size_t)(row0 + r) * 128 + c] * sc[c] + sh[c];    \
    }                                                                         \
    __syncthreads();                                                          \
    const int cg  = (t & 31) * 4;                                             \
    const int seg = t >> 5;                                                   \
    const int k0  = seg * 16;                                                 \
    float acc[4][4] = {};                                                     \
    float av[4][8];                                                           \
    _Pragma("unroll")                                                         \
    for (int kb = 0; kb < 16; kb += 8) {                                      \
      LOAD_ACT8(o3, k0 + kb, av);                                             \
      GEMM_BATCH8(Wn + cg, 128, k0 + kb, av, acc);                            \
    }                                                                         \
    _Pragma("unroll")                                                         \
    for (int r = 0; r < 4; ++r)                                               \
      *(float4*)&sP[seg][r * 128 + cg] = *(float4*)acc[r];                    \
    __syncthreads();                                                          \
    _Pragma("unroll")                                                         \
    for (int pass = 0; pass < 2; ++pass) {                                    \
      int idx = t + pass * 256;                                               \
      int col = idx & 127, r = idx >> 7;                                      \
      float x = ws[WS_C0 + col] + dem[row0 + r] * ws[WS_U + col];             \
      _Pragma("unroll")                                                       \
      for (int sg = 0; sg < 8; ++sg) x += sP[sg][r * 128 + col];              \
      (OUTPTR)[(size_t)(row0 + r) * 128 + col] = x;                           \
    }                                                                         \
  }

__global__ __launch_bounds__(256) void k_final(const float* __restrict__ Wn,
                                               const float* __restrict__ g2,
                                               const float* __restrict__ bb2,
                                               const float* __restrict__ dem,
                                               float* __restrict__ out,
                                               float* __restrict__ ws) {
  FIN_BODY(1, out)
}

__global__ __launch_bounds__(256) void p_final(const float* __restrict__ Wn,
                                               const float* __restrict__ g2,
                                               const float* __restrict__ bb2,
                                               const float* __restrict__ dem,
                                               float* __restrict__ out,  // unused
                                               float* __restrict__ ws) {
  FIN_BODY(REP_FIN, (ws + P_OUT))
}

extern "C" void kernel_launch(void* const* d_in, const int* in_sizes, int n_in,
                              void* d_out, int out_size, void* d_ws, size_t ws_size,
                              hipStream_t stream) {
  const float* cost   = (const float*)d_in[0];
  const float* dem    = (const float*)d_in[1];
  const float* rnd    = (const float*)d_in[2];
  const float* Wv     = (const float*)d_in[5];
  const float* mix1w  = (const float*)d_in[6];
  const float* mix1b  = (const float*)d_in[7];
  const float* mix2w  = (const float*)d_in[8];
  const float* mix2b  = (const float*)d_in[9];
  const float* Wo     = (const float*)d_in[10];
  const float* bo     = (const float*)d_in[11];
  const float* W1     = (const float*)d_in[12];
  const float* b1     = (const float*)d_in[13];
  const float* W2     = (const float*)d_in[14];
  const float* b2     = (const float*)d_in[15];
  const float* g1     = (const float*)d_in[16];
  const float* bb1    = (const float*)d_in[17];
  const float* g2     = (const float*)d_in[18];
  const float* bb2    = (const float*)d_in[19];
  const float* Wd     = (const float*)d_in[20];
  const float* bd     = (const float*)d_in[21];
  const float* Wn     = (const float*)d_in[22];
  const float* bnn    = (const float*)d_in[23];
  float* ws  = (float*)d_ws;
  float* out = (float*)d_out;

  // real (validated) chain
  hipLaunchKernelGGL(k_init,     dim3(6),   dim3(128), 0, stream, rnd, Wd, bd, Wn, bnn,
                     mix1w, mix1b, mix2w, mix2b, ws);
  hipLaunchKernelGGL(k_attn_mho, dim3(500), dim3(512), 0, stream, cost, Wv, Wo, bo, ws);
  hipLaunchKernelGGL(k_ffn,      dim3(250), dim3(512), 0, stream, W1, b1, g1, bb1, W2, b2, ws);
  hipLaunchKernelGGL(k_final,    dim3(500), dim3(256), 0, stream, Wn, g2, bb2, dem, out, ws);
  // probes (scratch only; d_out untouched)
  hipLaunchKernelGGL(p_attn,     dim3(500), dim3(512), 0, stream, cost, Wv, Wo, bo, ws);
  hipLaunchKernelGGL(p_ffn,      dim3(250), dim3(512), 0, stream, W1, b1, g1, bb1, W2, b2, ws);
  hipLaunchKernelGGL(p_final,    dim3(500), dim3(256), 0, stream, Wn, g2, bb2, dem, out, ws);
}

// Round 9
// 258.777 us; speedup vs baseline: 3.7476x; 3.7476x over previous
//
#include <hip/hip_runtime.h>
#include <hip/hip_bf16.h>

// Node_EncodingBlock on MI355X. Inputs fp32, output fp32.
// R9: 3-kernel chain (init folded in; BN via per-block partials, no atomics,
// no zero-init), LUT-based score MLP (exp(g_h) piecewise-exp, 256-bin linear
// interp, rel err ~3e-4), ffn at 500 blocks x 4 rows (full CU coverage).
// Ghost launches of kA (2000 blks) / kB (3000 blks) with scratch output bases
// -> identical codegen, >39.5us => visible in top-5: T_attn=gA/4, T_ffn=gB/6.

#define BN_EPS 1e-5f
// ws float offsets
#define WS_X1    256000     // [2000][128]
#define WS_X2    512000     // [2000][128]
#define BN1P     900000     // [500][256] per-block partials (sum|sq)
#define BN2P     1030000    // [500][256]
#define G_X1     1160000    // ghost scratch
#define G_BN1    1420000
#define G_X2     1560000
#define G_BN2    1820000

#define GB8_R2(WPTR, LDW, KIDX, ACT2D, ACC)                             \
  {                                                                     \
    float4 w[8];                                                        \
    _Pragma("unroll")                                                   \
    for (int u = 0; u < 8; ++u)                                         \
      w[u] = *(const float4*)((WPTR) + (size_t)((KIDX) + u) * (LDW));   \
    _Pragma("unroll")                                                   \
    for (int u = 0; u < 8; ++u) {                                       \
      _Pragma("unroll")                                                 \
      for (int r = 0; r < 2; ++r) {                                     \
        float a = ACT2D[r][u];                                          \
        ACC[r][0] = fmaf(a, w[u].x, ACC[r][0]);                         \
        ACC[r][1] = fmaf(a, w[u].y, ACC[r][1]);                         \
        ACC[r][2] = fmaf(a, w[u].z, ACC[r][2]);                         \
        ACC[r][3] = fmaf(a, w[u].w, ACC[r][3]);                         \
      }                                                                 \
    }                                                                   \
  }

#define LD_AV2(SRC_ROW0, SRC_ROW1, KIDX, ACT2D)                         \
  {                                                                     \
    float4 x0 = *(const float4*)&(SRC_ROW0)[(KIDX)];                    \
    float4 y0 = *(const float4*)&(SRC_ROW0)[(KIDX) + 4];                \
    float4 x1 = *(const float4*)&(SRC_ROW1)[(KIDX)];                    \
    float4 y1 = *(const float4*)&(SRC_ROW1)[(KIDX) + 4];                \
    ACT2D[0][0]=x0.x; ACT2D[0][1]=x0.y; ACT2D[0][2]=x0.z; ACT2D[0][3]=x0.w; \
    ACT2D[0][4]=y0.x; ACT2D[0][5]=y0.y; ACT2D[0][6]=y0.z; ACT2D[0][7]=y0.w; \
    ACT2D[1][0]=x1.x; ACT2D[1][1]=x1.y; ACT2D[1][2]=x1.z; ACT2D[1][3]=x1.w; \
    ACT2D[1][4]=y1.x; ACT2D[1][5]=y1.y; ACT2D[1][6]=y1.z; ACT2D[1][7]=y1.w; \
  }

// ---- kA: attention + multi_head_combine + BN1 partials --------------------
// grid%500 blocks x 512 thr, 4 rows/block. Self-contained: perm rank-count,
// MLP abs-params, exp(g) LUT built per block.
__global__ __launch_bounds__(512, 4) void k_attn(const float* __restrict__ cost,
                                                 const float* __restrict__ rnd,
                                                 const float* __restrict__ Wv,
                                                 const float* __restrict__ mix1w,
                                                 const float* __restrict__ mix1b,
                                                 const float* __restrict__ mix2w,
                                                 const float* __restrict__ mix2b,
                                                 const float* __restrict__ Wo,
                                                 const float* __restrict__ bo,
                                                 float* __restrict__ ws,
                                                 int xbase, int pbase) {
  __shared__ float scost[4][512];
  __shared__ float2 lut[8 * 256];      // 16 KB: {T, dT} per (head, bin)
  __shared__ float aw[32][132];
  __shared__ float soc[4][132];
  __shared__ float sP[8][512];         // phase C/D partials; LUT-build scratch
  __shared__ float svr[128];
  __shared__ int   sperm[128];
  __shared__ float mu[8][16], mr[8][16], mA[8], mB[8];
  __shared__ float sS[512], sQ[512];
  const int t = threadIdx.x;
  const int lane = t & 63;
  const int blk = blockIdx.x % 500;
  const int row0 = blk * 4;
  const int b = blk / 125;

  // stage cost rows ([4][512], zero-padded past 500)
  {
    int rr = t >> 7, i4 = t & 127;
    *(float4*)&scost[rr][i4 * 4] = (i4 < 125)
        ? *(const float4*)(cost + (size_t)(row0 + rr) * 500 + i4 * 4)
        : float4{0.f, 0.f, 0.f, 0.f};
  }
  if (t < 128) svr[t] = rnd[b * 128 + t];
  __syncthreads();
  // perm: stable ascending argsort by rank count
  if (t < 128) {
    float vt = svr[t];
    int rank = 0;
    for (int j = 0; j < 128; ++j) {
      float vj = svr[j];
      rank += (vj < vt) || (vj == vt && j < t);
    }
    sperm[rank] = t;
    // MLP abs-form params: g(c) = A c + B + sum u_s |c - r_s|
    int h = t >> 4, s = t & 15;
    float w1  = mix1w[h * 32 + 16 + s];
    float b1v = mix1b[h * 16 + s];
    float w2  = mix2w[h * 16 + s];
    bool tiny = fabsf(w1) < 1e-20f;
    float us = tiny ? 0.f : 0.5f * w2 * fabsf(w1);
    float rs = tiny ? 0.f : -b1v / w1;
    float Ap = 0.5f * w2 * w1;
    float Bp = 0.5f * w2 * b1v + (tiny ? 0.5f * w2 * fabsf(b1v) : 0.f);
    mu[h][s] = us; mr[h][s] = rs;
#pragma unroll
    for (int off = 1; off < 16; off <<= 1) {
      Ap += __shfl_xor(Ap, off);
      Bp += __shfl_xor(Bp, off);
    }
    if (s == 0) { mA[h] = Ap; mB[h] = Bp + mix2b[h]; }
  }
  __syncthreads();
  // LUT pass 1: raw T[h][i] = exp(g_h(i/255)) into sP scratch
  float* traw = &sP[0][0];
  if (t < 257) {
    float x = (float)t * (1.f / 255.f);
    for (int h = 0; h < 8; ++h) {
      float g = fmaf(x, mA[h], mB[h]);
#pragma unroll
      for (int s = 0; s < 16; ++s)
        g = fmaf(fabsf(x - mr[h][s]), mu[h][s], g);
      traw[h * 257 + t] = __expf(g);
    }
  }
  __syncthreads();
  // LUT pass 2: pack {T, T[i+1]-T[i]}
#pragma unroll
  for (int p = 0; p < 4; ++p) {
    int e = t + p * 512;
    int h = e >> 8, i = e & 255;
    float a = traw[h * 257 + i];
    lut[e] = float2{a, traw[h * 257 + i + 1] - a};
  }
  __syncthreads();
  // phase B: wave (r, head-half): LUT scores + softmax -> aggregated weights
  {
    const int wid = t >> 6;
    const int r  = wid & 3;
    const int h0 = (wid >> 2) * 4;
    float cv8[8];
#pragma unroll
    for (int ii = 0; ii < 8; ++ii) cv8[ii] = scost[r][ii * 64 + lane];
    for (int h = h0; h < h0 + 4; ++h) {
      const float2* lh = &lut[h * 256];
      float wsum = 0.f, a0 = 0.f, a1 = 0.f;
#pragma unroll
      for (int ii = 0; ii < 8; ++ii) {
        float u = cv8[ii] * 255.f;
        int i = (int)u;
        float f = u - (float)i;
        float2 td = lh[i];
        float e = fmaf(td.y, f, td.x);
        if (ii == 7 && lane >= 52) e = 0.f;   // mask m >= 500
        wsum += e;
        if (ii & 1) a1 += e; else a0 += e;
      }
#pragma unroll
      for (int off = 32; off; off >>= 1) wsum += __shfl_xor(wsum, off);
      float inv = 1.f / wsum;
      aw[r * 8 + h][lane]      = a0 * inv;
      aw[r * 8 + h][64 + lane] = a1 * inv;
    }
  }
  __syncthreads();
  // phase C: oc[r][c] = sum_j aw[r*8+(c>>4)][j] * Wv[perm[j]][c]; j-split 4
  {
    const int c  = t & 127;
    const int jh = t >> 7;
    const int h  = c >> 4;
    float acc4[4] = {0.f, 0.f, 0.f, 0.f};
    for (int jb = jh * 32; jb < jh * 32 + 32; jb += 8) {
      int rows[8];
#pragma unroll
      for (int u = 0; u < 8; ++u) rows[u] = sperm[jb + u];
      float wv8[8];
#pragma unroll
      for (int u = 0; u < 8; ++u) wv8[u] = Wv[(size_t)rows[u] * 128 + c];
#pragma unroll
      for (int r = 0; r < 4; ++r) {
        float4 aa = *(const float4*)&aw[r * 8 + h][jb];
        float4 ab = *(const float4*)&aw[r * 8 + h][jb + 4];
        acc4[r] = fmaf(aa.x, wv8[0], acc4[r]);
        acc4[r] = fmaf(aa.y, wv8[1], acc4[r]);
        acc4[r] = fmaf(aa.z, wv8[2], acc4[r]);
        acc4[r] = fmaf(aa.w, wv8[3], acc4[r]);
        acc4[r] = fmaf(ab.x, wv8[4], acc4[r]);
        acc4[r] = fmaf(ab.y, wv8[5], acc4[r]);
        acc4[r] = fmaf(ab.z, wv8[6], acc4[r]);
        acc4[r] = fmaf(ab.w, wv8[7], acc4[r]);
      }
    }
#pragma unroll
    for (int r = 0; r < 4; ++r) sP[jh][r * 128 + c] = acc4[r];
  }
  __syncthreads();
  {
    int r = t >> 7, c = t & 127;
    soc[r][c] = sP[0][r * 128 + c] + sP[1][r * 128 + c] +
                sP[2][r * 128 + c] + sP[3][r * 128 + c];
  }
  __syncthreads();
  // phase D: X1 = soc @ Wo + bo; k-split 8 x row-half 2
  {
    const int cg  = (t & 31) * 4;
    const int seg = (t >> 5) & 7;
    const int rh  = t >> 8;
    const int k0  = seg * 16;
    float acc[2][4] = {};
    float av[2][8];
#pragma unroll
    for (int kb = 0; kb < 16; kb += 8) {
      LD_AV2(soc[rh * 2], soc[rh * 2 + 1], k0 + kb, av);
      GB8_R2(Wo + cg, 128, k0 + kb, av, acc);
    }
#pragma unroll
    for (int r = 0; r < 2; ++r)
      *(float4*)&sP[seg][(rh * 2 + r) * 128 + cg] = *(float4*)acc[r];
  }
  __syncthreads();
  {
    int r = t >> 7, col = t & 127;
    float x = bo[col];
#pragma unroll
    for (int sg = 0; sg < 8; ++sg) x += sP[sg][r * 128 + col];
    ws[xbase + (size_t)(row0 + r) * 128 + col] = x;
    sS[t] = x; sQ[t] = x * x;
  }
  __syncthreads();
  if (t < 128) {
    ws[pbase + blk * 256 + t]       = sS[t] + sS[t+128] + sS[t+256] + sS[t+384];
    ws[pbase + blk * 256 + 128 + t] = sQ[t] + sQ[t+128] + sQ[t+256] + sQ[t+384];
  }
}

// ---- kB: BN1(reduce partials) -> FFN -> X2 + BN2 partials -----------------
// grid%500 blocks x 512 thr, 4 rows/block.
__global__ __launch_bounds__(512, 4) void k_ffn(const float* __restrict__ W1,
                                                const float* __restrict__ b1,
                                                const float* __restrict__ g1,
                                                const float* __restrict__ bb1,
                                                const float* __restrict__ W2,
                                                const float* __restrict__ b2,
                                                float* __restrict__ ws,
                                                int x1base, int p1base,
                                                int x2base, int p2base) {
  __shared__ float o1[4][128];
  __shared__ float sY[4][512];
  __shared__ float sP2[8][4][128];     // 16 KB; first 8 KB doubles as GEMM1 pf
  __shared__ float sc[128], sh[128];
  __shared__ float red[4][128], redq[4][128];
  __shared__ float sS[512], sQ[512];
  const int t = threadIdx.x;
  const int blk = blockIdx.x % 500;
  const int row0 = blk * 4;
  // BN1 stats: reduce 500 per-block partials (4 groups x 125)
  {
    const int c = t & 127, g = t >> 7;
    float s = 0.f, q = 0.f;
#pragma unroll 5
    for (int j = g * 125; j < g * 125 + 125; ++j) {
      s += ws[p1base + j * 256 + c];
      q += ws[p1base + j * 256 + 128 + c];
    }
    red[g][c] = s; redq[g][c] = q;
  }
  __syncthreads();
  if (t < 128) {
    float s = red[0][t] + red[1][t] + red[2][t] + red[3][t];
    float q = redq[0][t] + redq[1][t] + redq[2][t] + redq[3][t];
    float m = s * 5e-4f;
    float v = q * 5e-4f - m * m;
    float rsq = rsqrtf(v + BN_EPS);
    float scv = g1[t] * rsq;
    sc[t] = scv; sh[t] = bb1[t] - m * scv;
  }
  __syncthreads();
  {
    int r = t >> 7, c = t & 127;
    o1[r][c] = ws[x1base + (size_t)(row0 + r) * 128 + c] * sc[c] + sh[c];
  }
  __syncthreads();
  // GEMM1 (128->512): cg(128x4c) x kseg(2x64k) x rh(2x2rows)
  {
    const int cg   = (t & 127) * 4;
    const int kseg = (t >> 7) & 1;
    const int rh   = t >> 8;
    const int kb0  = kseg * 64;
    float acc[2][4] = {};
    float av[2][8];
#pragma unroll
    for (int k0 = 0; k0 < 64; k0 += 8) {
      LD_AV2(o1[rh * 2], o1[rh * 2 + 1], kb0 + k0, av);
      GB8_R2(W1 + cg, 512, kb0 + k0, av, acc);
    }
    float* pf = &sP2[0][0][0];         // [4][512]
    if (kseg == 1) {
#pragma unroll
      for (int r = 0; r < 2; ++r)
        *(float4*)(pf + (size_t)(rh * 2 + r) * 512 + cg) = *(float4*)acc[r];
    }
    __syncthreads();
    if (kseg == 0) {
      float4 bv = *(const float4*)(b1 + cg);
#pragma unroll
      for (int r = 0; r < 2; ++r) {
        float4 p = *(float4*)(pf + (size_t)(rh * 2 + r) * 512 + cg);
        float4 y = {fmaxf(acc[r][0] + p.x + bv.x, 0.f),
                    fmaxf(acc[r][1] + p.y + bv.y, 0.f),
                    fmaxf(acc[r][2] + p.z + bv.z, 0.f),
                    fmaxf(acc[r][3] + p.w + bv.w, 0.f)};
        *(float4*)&sY[rh * 2 + r][cg] = y;
      }
    }
  }
  __syncthreads();
  // GEMM2 (512->128): cg(32x4c) x kseg(8x64k) x rh(2x2rows)
  {
    const int cg   = (t & 31) * 4;
    const int kseg = (t >> 5) & 7;
    const int rh   = t >> 8;
    const int k0   = kseg * 64;
    float acc[2][4] = {};
    float av[2][8];
#pragma unroll
    for (int kb = 0; kb < 64; kb += 8) {
      LD_AV2(sY[rh * 2], sY[rh * 2 + 1], k0 + kb, av);
      GB8_R2(W2 + cg, 128, k0 + kb, av, acc);
    }
    // pf reads finished before the sync after GEMM1; sY distinct region: safe
#pragma unroll
    for (int r = 0; r < 2; ++r)
      *(float4*)&sP2[kseg][rh * 2 + r][cg] = *(float4*)acc[r];
  }
  __syncthreads();
  {
    int r = t >> 7, c = t & 127;
    float x = b2[c] + o1[r][c];
#pragma unroll
    for (int sg = 0; sg < 8; ++sg) x += sP2[sg][r][c];
    ws[x2base + (size_t)(row0 + r) * 128 + c] = x;
    sS[t] = x; sQ[t] = x * x;
  }
  __syncthreads();
  if (t < 128) {
    ws[p2base + blk * 256 + t]       = sS[t] + sS[t+128] + sS[t+256] + sS[t+384];
    ws[p2base + blk * 256 + 128 + t] = sQ[t] + sQ[t+128] + sQ[t+256] + sQ[t+384];
  }
}

// ---- kC: BN2(reduce) -> out3 @ Wn_top + demand*U + C0 -> out --------------
// 500 blocks x 512 thr, 4 rows/block. U/C0 computed per block.
__global__ __launch_bounds__(512, 4) void k_final(const float* __restrict__ Wn,
                                                  const float* __restrict__ g2,
                                                  const float* __restrict__ bb2,
                                                  const float* __restrict__ dem,
                                                  const float* __restrict__ bnn,
                                                  const float* __restrict__ Wd,
                                                  const float* __restrict__ bd,
                                                  float* __restrict__ out,
                                                  float* __restrict__ ws,
                                                  int x2src, int p2src) {
  __shared__ float o3[4][132];
  __shared__ float sP[8][4][128];
  __shared__ float sc[128], sh[128];
  __shared__ float sU[128], sC0[128];
  __shared__ float red[4][128], redq[4][128];
  const int t = threadIdx.x;
  const int blk = blockIdx.x;
  const int row0 = blk * 4;
  // BN2 stats reduce
  {
    const int c = t & 127, g = t >> 7;
    float s = 0.f, q = 0.f;
#pragma unroll 5
    for (int j = g * 125; j < g * 125 + 125; ++j) {
      s += ws[p2src + j * 256 + c];
      q += ws[p2src + j * 256 + 128 + c];
    }
    red[g][c] = s; redq[g][c] = q;
  }
  __syncthreads();
  if (t < 128) {
    float s = red[0][t] + red[1][t] + red[2][t] + red[3][t];
    float q = redq[0][t] + redq[1][t] + redq[2][t] + redq[3][t];
    float m = s * 5e-4f;
    float v = q * 5e-4f - m * m;
    float rsq = rsqrtf(v + BN_EPS);
    float scv = g2[t] * rsq;
    sc[t] = scv; sh[t] = bb2[t] - m * scv;
  }
  __syncthreads();
  // U[c] = Wd @ Wn_bot[:,c]; C0[c] = bd @ Wn_bot[:,c] + bn_node[c]; e-split 4
  {
    const int c = t & 127, g = t >> 7;
    float u = 0.f, c0 = 0.f;
#pragma unroll 8
    for (int e = g * 32; e < g * 32 + 32; ++e) {
      float wn = Wn[(size_t)(128 + e) * 128 + c];
      u  = fmaf(Wd[e], wn, u);
      c0 = fmaf(bd[e], wn, c0);
    }
    red[g][c] = u; redq[g][c] = c0;
  }
  __syncthreads();
  if (t < 128) {
    sU[t]  = red[0][t] + red[1][t] + red[2][t] + red[3][t];
    sC0[t] = redq[0][t] + redq[1][t] + redq[2][t] + redq[3][t] + bnn[t];
  }
  {
    int r = t >> 7, c = t & 127;
    o3[r][c] = ws[x2src + (size_t)(row0 + r) * 128 + c];
  }
  __syncthreads();
  {
    int r = t >> 7, c = t & 127;
    o3[r][c] = o3[r][c] * sc[c] + sh[c];
  }
  __syncthreads();
  // GEMM Wn_top: cg(32x4c) x seg(8x16k) x rh(2x2rows)
  {
    const int cg  = (t & 31) * 4;
    const int seg = (t >> 5) & 7;
    const int rh  = t >> 8;
    const int k0  = seg * 16;
    float acc[2][4] = {};
    float av[2][8];
#pragma unroll
    for (int kb = 0; kb < 16; kb += 8) {
      LD_AV2(o3[rh * 2], o3[rh * 2 + 1], k0 + kb, av);
      GB8_R2(Wn + cg, 128, k0 + kb, av, acc);
    }
#pragma unroll
    for (int r = 0; r < 2; ++r)
      *(float4*)&sP[seg][rh * 2 + r][cg] = *(float4*)acc[r];
  }
  __syncthreads();
  {
    int r = t >> 7, c = t & 127;
    float x = sC0[c] + dem[row0 + r] * sU[c];
#pragma unroll
    for (int sg = 0; sg < 8; ++sg) x += sP[sg][r][c];
    out[(size_t)(row0 + r) * 128 + c] = x;
  }
}

extern "C" void kernel_launch(void* const* d_in, const int* in_sizes, int n_in,
                              void* d_out, int out_size, void* d_ws, size_t ws_size,
                              hipStream_t stream) {
  const float* cost   = (const float*)d_in[0];
  const float* dem    = (const float*)d_in[1];
  const float* rnd    = (const float*)d_in[2];
  // d_in[3] Wq, d_in[4] Wk unused (q == 0)
  const float* Wv     = (const float*)d_in[5];
  const float* mix1w  = (const float*)d_in[6];
  const float* mix1b  = (const float*)d_in[7];
  const float* mix2w  = (const float*)d_in[8];
  const float* mix2b  = (const float*)d_in[9];
  const float* Wo     = (const float*)d_in[10];
  const float* bo     = (const float*)d_in[11];
  const float* W1     = (const float*)d_in[12];
  const float* b1     = (const float*)d_in[13];
  const float* W2     = (const float*)d_in[14];
  const float* b2     = (const float*)d_in[15];
  const float* g1     = (const float*)d_in[16];
  const float* bb1    = (const float*)d_in[17];
  const float* g2     = (const float*)d_in[18];
  const float* bb2    = (const float*)d_in[19];
  const float* Wd     = (const float*)d_in[20];
  const float* bd     = (const float*)d_in[21];
  const float* Wn     = (const float*)d_in[22];
  const float* bnn    = (const float*)d_in[23];
  float* ws  = (float*)d_ws;
  float* out = (float*)d_out;

  // real chain
  hipLaunchKernelGGL(k_attn,  dim3(500), dim3(512), 0, stream, cost, rnd, Wv,
                     mix1w, mix1b, mix2w, mix2b, Wo, bo, ws, WS_X1, BN1P);
  hipLaunchKernelGGL(k_ffn,   dim3(500), dim3(512), 0, stream, W1, b1, g1, bb1,
                     W2, b2, ws, WS_X1, BN1P, WS_X2, BN2P);
  hipLaunchKernelGGL(k_final, dim3(500), dim3(512), 0, stream, Wn, g2, bb2, dem,
                     bnn, Wd, bd, out, ws, WS_X2, BN2P);
  // ghosts: identical kernels, scratch bases, scaled grids (timing probes)
  hipLaunchKernelGGL(k_attn,  dim3(2000), dim3(512), 0, stream, cost, rnd, Wv,
                     mix1w, mix1b, mix2w, mix2b, Wo, bo, ws, G_X1, G_BN1);
  hipLaunchKernelGGL(k_ffn,   dim3(3000), dim3(512), 0, stream, W1, b1, g1, bb1,
                     W2, b2, ws, WS_X1, BN1P, G_X2, G_BN2);
}

// Round 10
// 54.806 us; speedup vs baseline: 17.6953x; 4.7217x over previous
//
#include <hip/hip_runtime.h>
#include <hip/hip_bf16.h>

// Node_EncodingBlock on MI355X. Inputs fp32, output fp32.
// R10: ghosts removed. BN stats via atomics + 2KB hipMemsetAsync zero-init
// (kills the 256MB/launch partial-reduce redundancy of R9). k_ffn at 250
// blocks x 8 rows (halves weight L2 traffic). U/C0 computed once in k_ffn
// block 0 (kills 500x64KB redundant Wn_bot reads in k_final).
// Breakdown from R9 ghost telemetry: attn~9.5us, ffn 29->~9, final ~5.

#define BN_EPS 1e-5f
// ws float offsets
#define WS_X1    256000     // [2000][128]
#define WS_X2    512000     // [2000][128]
#define WS_SUM1  768000     // [128]   (memset-zeroed, atomic-accumulated)
#define WS_SQ1   768128
#define WS_SUM2  768256
#define WS_SQ2   768384
#define WS_UV    768512     // [128] U   (written by k_ffn block 0)
#define WS_C0V   768640     // [128] C0

// 4-row batched GEMM micro-step
#define GEMM_BATCH8(WPTR, LDW, KIDX, ACT2D, ACC)                        \
  {                                                                     \
    float4 w[8];                                                        \
    _Pragma("unroll")                                                   \
    for (int u = 0; u < 8; ++u)                                         \
      w[u] = *(const float4*)((WPTR) + (size_t)((KIDX) + u) * (LDW));   \
    _Pragma("unroll")                                                   \
    for (int u = 0; u < 8; ++u) {                                       \
      _Pragma("unroll")                                                 \
      for (int r = 0; r < 4; ++r) {                                     \
        float a = ACT2D[r][u];                                          \
        ACC[r][0] = fmaf(a, w[u].x, ACC[r][0]);                         \
        ACC[r][1] = fmaf(a, w[u].y, ACC[r][1]);                         \
        ACC[r][2] = fmaf(a, w[u].z, ACC[r][2]);                         \
        ACC[r][3] = fmaf(a, w[u].w, ACC[r][3]);                         \
      }                                                                 \
    }                                                                   \
  }

#define LOAD_ACT8(SRC2D, KIDX, ACT2D)                                   \
  {                                                                     \
    _Pragma("unroll")                                                   \
    for (int r = 0; r < 4; ++r) {                                       \
      float4 x = *(const float4*)&SRC2D[r][(KIDX)];                     \
      float4 y = *(const float4*)&SRC2D[r][(KIDX) + 4];                 \
      ACT2D[r][0] = x.x; ACT2D[r][1] = x.y; ACT2D[r][2] = x.z;          \
      ACT2D[r][3] = x.w; ACT2D[r][4] = y.x; ACT2D[r][5] = y.y;          \
      ACT2D[r][6] = y.z; ACT2D[r][7] = y.w;                             \
    }                                                                   \
  }

// 2-row variants
#define GB8_R2(WPTR, LDW, KIDX, ACT2D, ACC)                             \
  {                                                                     \
    float4 w[8];                                                        \
    _Pragma("unroll")                                                   \
    for (int u = 0; u < 8; ++u)                                         \
      w[u] = *(const float4*)((WPTR) + (size_t)((KIDX) + u) * (LDW));   \
    _Pragma("unroll")                                                   \
    for (int u = 0; u < 8; ++u) {                                       \
      _Pragma("unroll")                                                 \
      for (int r = 0; r < 2; ++r) {                                     \
        float a = ACT2D[r][u];                                          \
        ACC[r][0] = fmaf(a, w[u].x, ACC[r][0]);                         \
        ACC[r][1] = fmaf(a, w[u].y, ACC[r][1]);                         \
        ACC[r][2] = fmaf(a, w[u].z, ACC[r][2]);                         \
        ACC[r][3] = fmaf(a, w[u].w, ACC[r][3]);                         \
      }                                                                 \
    }                                                                   \
  }

#define LD_AV2(SRC_ROW0, SRC_ROW1, KIDX, ACT2D)                         \
  {                                                                     \
    float4 x0 = *(const float4*)&(SRC_ROW0)[(KIDX)];                    \
    float4 y0 = *(const float4*)&(SRC_ROW0)[(KIDX) + 4];                \
    float4 x1 = *(const float4*)&(SRC_ROW1)[(KIDX)];                    \
    float4 y1 = *(const float4*)&(SRC_ROW1)[(KIDX) + 4];                \
    ACT2D[0][0]=x0.x; ACT2D[0][1]=x0.y; ACT2D[0][2]=x0.z; ACT2D[0][3]=x0.w; \
    ACT2D[0][4]=y0.x; ACT2D[0][5]=y0.y; ACT2D[0][6]=y0.z; ACT2D[0][7]=y0.w; \
    ACT2D[1][0]=x1.x; ACT2D[1][1]=x1.y; ACT2D[1][2]=x1.z; ACT2D[1][3]=x1.w; \
    ACT2D[1][4]=y1.x; ACT2D[1][5]=y1.y; ACT2D[1][6]=y1.z; ACT2D[1][7]=y1.w; \
  }

// ---- kA: attention + multi_head_combine + BN1 stats (atomic) --------------
// 500 blocks x 512 thr, 4 rows/block. Self-contained: perm rank-count,
// MLP abs-params, exp(g) LUT built per block.
__global__ __launch_bounds__(512, 4) void k_attn(const float* __restrict__ cost,
                                                 const float* __restrict__ rnd,
                                                 const float* __restrict__ Wv,
                                                 const float* __restrict__ mix1w,
                                                 const float* __restrict__ mix1b,
                                                 const float* __restrict__ mix2w,
                                                 const float* __restrict__ mix2b,
                                                 const float* __restrict__ Wo,
                                                 const float* __restrict__ bo,
                                                 float* __restrict__ ws) {
  __shared__ float scost[4][512];
  __shared__ float2 lut[8 * 256];      // 16 KB: {T, dT} per (head, bin)
  __shared__ float aw[32][132];
  __shared__ float soc[4][132];
  __shared__ float sP[8][512];         // phase C/D partials; LUT-build scratch
  __shared__ float svr[128];
  __shared__ int   sperm[128];
  __shared__ float mu[8][16], mr[8][16], mA[8], mB[8];
  __shared__ float sS[512], sQ[512];
  const int t = threadIdx.x;
  const int lane = t & 63;
  const int blk = blockIdx.x;
  const int row0 = blk * 4;
  const int b = blk / 125;

  {
    int rr = t >> 7, i4 = t & 127;
    *(float4*)&scost[rr][i4 * 4] = (i4 < 125)
        ? *(const float4*)(cost + (size_t)(row0 + rr) * 500 + i4 * 4)
        : float4{0.f, 0.f, 0.f, 0.f};
  }
  if (t < 128) svr[t] = rnd[b * 128 + t];
  __syncthreads();
  if (t < 128) {
    float vt = svr[t];
    int rank = 0;
    for (int j = 0; j < 128; ++j) {
      float vj = svr[j];
      rank += (vj < vt) || (vj == vt && j < t);
    }
    sperm[rank] = t;
    // abs-form MLP params: g(c) = A c + B + sum u_s |c - r_s|
    int h = t >> 4, s = t & 15;
    float w1  = mix1w[h * 32 + 16 + s];
    float b1v = mix1b[h * 16 + s];
    float w2  = mix2w[h * 16 + s];
    bool tiny = fabsf(w1) < 1e-20f;
    float us = tiny ? 0.f : 0.5f * w2 * fabsf(w1);
    float rs = tiny ? 0.f : -b1v / w1;
    float Ap = 0.5f * w2 * w1;
    float Bp = 0.5f * w2 * b1v + (tiny ? 0.5f * w2 * fabsf(b1v) : 0.f);
    mu[h][s] = us; mr[h][s] = rs;
#pragma unroll
    for (int off = 1; off < 16; off <<= 1) {
      Ap += __shfl_xor(Ap, off);
      Bp += __shfl_xor(Bp, off);
    }
    if (s == 0) { mA[h] = Ap; mB[h] = Bp + mix2b[h]; }
  }
  __syncthreads();
  // LUT pass 1: raw T[h][i] = exp(g_h(i/255)) into sP scratch
  float* traw = &sP[0][0];
  if (t < 257) {
    float x = (float)t * (1.f / 255.f);
    for (int h = 0; h < 8; ++h) {
      float g = fmaf(x, mA[h], mB[h]);
#pragma unroll
      for (int s = 0; s < 16; ++s)
        g = fmaf(fabsf(x - mr[h][s]), mu[h][s], g);
      traw[h * 257 + t] = __expf(g);
    }
  }
  __syncthreads();
#pragma unroll
  for (int p = 0; p < 4; ++p) {
    int e = t + p * 512;
    int h = e >> 8, i = e & 255;
    float a = traw[h * 257 + i];
    lut[e] = float2{a, traw[h * 257 + i + 1] - a};
  }
  __syncthreads();
  // phase B: wave (r, head-half): LUT scores + softmax -> aggregated weights
  {
    const int wid = t >> 6;
    const int r  = wid & 3;
    const int h0 = (wid >> 2) * 4;
    float cv8[8];
#pragma unroll
    for (int ii = 0; ii < 8; ++ii) cv8[ii] = scost[r][ii * 64 + lane];
    for (int h = h0; h < h0 + 4; ++h) {
      const float2* lh = &lut[h * 256];
      float wsum = 0.f, a0 = 0.f, a1 = 0.f;
#pragma unroll
      for (int ii = 0; ii < 8; ++ii) {
        float u = cv8[ii] * 255.f;
        int i = (int)u;
        float f = u - (float)i;
        float2 td = lh[i];
        float e = fmaf(td.y, f, td.x);
        if (ii == 7 && lane >= 52) e = 0.f;   // mask m >= 500
        wsum += e;
        if (ii & 1) a1 += e; else a0 += e;
      }
#pragma unroll
      for (int off = 32; off; off >>= 1) wsum += __shfl_xor(wsum, off);
      float inv = 1.f / wsum;
      aw[r * 8 + h][lane]      = a0 * inv;
      aw[r * 8 + h][64 + lane] = a1 * inv;
    }
  }
  __syncthreads();
  // phase C: oc[r][c] = sum_j aw[r*8+(c>>4)][j] * Wv[perm[j]][c]; j-split 4
  {
    const int c  = t & 127;
    const int jh = t >> 7;
    const int h  = c >> 4;
    float acc4[4] = {0.f, 0.f, 0.f, 0.f};
    for (int jb = jh * 32; jb < jh * 32 + 32; jb += 8) {
      int rows[8];
#pragma unroll
      for (int u = 0; u < 8; ++u) rows[u] = sperm[jb + u];
      float wv8[8];
#pragma unroll
      for (int u = 0; u < 8; ++u) wv8[u] = Wv[(size_t)rows[u] * 128 + c];
#pragma unroll
      for (int r = 0; r < 4; ++r) {
        float4 aa = *(const float4*)&aw[r * 8 + h][jb];
        float4 ab = *(const float4*)&aw[r * 8 + h][jb + 4];
        acc4[r] = fmaf(aa.x, wv8[0], acc4[r]);
        acc4[r] = fmaf(aa.y, wv8[1], acc4[r]);
        acc4[r] = fmaf(aa.z, wv8[2], acc4[r]);
        acc4[r] = fmaf(aa.w, wv8[3], acc4[r]);
        acc4[r] = fmaf(ab.x, wv8[4], acc4[r]);
        acc4[r] = fmaf(ab.y, wv8[5], acc4[r]);
        acc4[r] = fmaf(ab.z, wv8[6], acc4[r]);
        acc4[r] = fmaf(ab.w, wv8[7], acc4[r]);
      }
    }
#pragma unroll
    for (int r = 0; r < 4; ++r) sP[jh][r * 128 + c] = acc4[r];
  }
  __syncthreads();
  {
    int r = t >> 7, c = t & 127;
    soc[r][c] = sP[0][r * 128 + c] + sP[1][r * 128 + c] +
                sP[2][r * 128 + c] + sP[3][r * 128 + c];
  }
  __syncthreads();
  // phase D: X1 = soc @ Wo + bo; k-split 8 x row-half 2
  {
    const int cg  = (t & 31) * 4;
    const int seg = (t >> 5) & 7;
    const int rh  = t >> 8;
    const int k0  = seg * 16;
    float acc[2][4] = {};
    float av[2][8];
#pragma unroll
    for (int kb = 0; kb < 16; kb += 8) {
      LD_AV2(soc[rh * 2], soc[rh * 2 + 1], k0 + kb, av);
      GB8_R2(Wo + cg, 128, k0 + kb, av, acc);
    }
#pragma unroll
    for (int r = 0; r < 2; ++r)
      *(float4*)&sP[seg][(rh * 2 + r) * 128 + cg] = *(float4*)acc[r];
  }
  __syncthreads();
  {
    int r = t >> 7, col = t & 127;
    float x = bo[col];
#pragma unroll
    for (int sg = 0; sg < 8; ++sg) x += sP[sg][r * 128 + col];
    ws[WS_X1 + (size_t)(row0 + r) * 128 + col] = x;
    sS[t] = x; sQ[t] = x * x;
  }
  __syncthreads();
  if (t < 128) {
    atomicAdd(ws + WS_SUM1 + t, sS[t] + sS[t+128] + sS[t+256] + sS[t+384]);
    atomicAdd(ws + WS_SQ1 + t, sQ[t] + sQ[t+128] + sQ[t+256] + sQ[t+384]);
  }
}

// ---- kB: BN1 -> FFN -> X2 + BN2 stats (atomic); block 0 computes U/C0 -----
// 250 blocks x 512 thr, 8 rows/block.
__global__ __launch_bounds__(512) void k_ffn(const float* __restrict__ W1,
                                             const float* __restrict__ b1,
                                             const float* __restrict__ g1,
                                             const float* __restrict__ bb1,
                                             const float* __restrict__ W2,
                                             const float* __restrict__ b2,
                                             const float* __restrict__ Wn,
                                             const float* __restrict__ Wd,
                                             const float* __restrict__ bd,
                                             const float* __restrict__ bnn,
                                             float* __restrict__ ws) {
  __shared__ float o1[8][128];
  __shared__ float sY[8][512];         // 16 KB
  __shared__ float sP2[8][8][128];     // 32 KB; first 16 KB doubles as GEMM1 pf
  __shared__ float sS[512], sQ[512];
  const int t = threadIdx.x;
  const int row0 = blockIdx.x * 8;
  const int c0 = t & 127;
  // BN1 affine from accumulated stats (256-float read, broadcast)
  float m1 = ws[WS_SUM1 + c0] * 5e-4f;
  float v1 = ws[WS_SQ1 + c0] * 5e-4f - m1 * m1;
  float scv = g1[c0] * rsqrtf(v1 + BN_EPS);
  float shv = bb1[c0] - m1 * scv;
  {
    int r0 = t >> 7;
    o1[r0][c0]     = ws[WS_X1 + (size_t)(row0 + r0) * 128 + c0] * scv + shv;
    o1[r0 + 4][c0] = ws[WS_X1 + (size_t)(row0 + r0 + 4) * 128 + c0] * scv + shv;
  }
  __syncthreads();
  // GEMM1 (128->512): cg(128x4c) x kseg(2x64k) x rh(2x4rows)
  {
    const int cg   = (t & 127) * 4;
    const int kseg = (t >> 7) & 1;
    const int rh   = t >> 8;
    const int kb0  = kseg * 64;
    float acc[4][4] = {};
    float av[4][8];
#pragma unroll
    for (int k0 = 0; k0 < 64; k0 += 8) {
      LOAD_ACT8((o1 + rh * 4), kb0 + k0, av);
      GEMM_BATCH8(W1 + cg, 512, kb0 + k0, av, acc);
    }
    float* pf = &sP2[0][0][0];         // [8][512]
    if (kseg == 1) {
#pragma unroll
      for (int r = 0; r < 4; ++r)
        *(float4*)(pf + (size_t)(rh * 4 + r) * 512 + cg) = *(float4*)acc[r];
    }
    __syncthreads();
    if (kseg == 0) {
      float4 bv = *(const float4*)(b1 + cg);
#pragma unroll
      for (int r = 0; r < 4; ++r) {
        float4 p = *(float4*)(pf + (size_t)(rh * 4 + r) * 512 + cg);
        float4 y = {fmaxf(acc[r][0] + p.x + bv.x, 0.f),
                    fmaxf(acc[r][1] + p.y + bv.y, 0.f),
                    fmaxf(acc[r][2] + p.z + bv.z, 0.f),
                    fmaxf(acc[r][3] + p.w + bv.w, 0.f)};
        *(float4*)&sY[rh * 4 + r][cg] = y;
      }
    }
  }
  __syncthreads();
  // GEMM2 (512->128): cg(32x4c) x kseg(8x64k) x rh(2x4rows)
  {
    const int cg   = (t & 31) * 4;
    const int kseg = (t >> 5) & 7;
    const int rh   = t >> 8;
    const int k0   = kseg * 64;
    float acc[4][4] = {};
    float av[4][8];
#pragma unroll
    for (int kb = 0; kb < 64; kb += 8) {
      LOAD_ACT8((sY + rh * 4), k0 + kb, av);
      GEMM_BATCH8(W2 + cg, 128, k0 + kb, av, acc);
    }
#pragma unroll
    for (int r = 0; r < 4; ++r)
      *(float4*)&sP2[kseg][rh * 4 + r][cg] = *(float4*)acc[r];
  }
  __syncthreads();
  float s = 0.f, q = 0.f;
#pragma unroll
  for (int pass = 0; pass < 2; ++pass) {
    int idx = t + pass * 512;
    int col = idx & 127, r = idx >> 7;
    float x = b2[col] + o1[r][col];
#pragma unroll
    for (int sg = 0; sg < 8; ++sg) x += sP2[sg][r][col];
    ws[WS_X2 + (size_t)(row0 + r) * 128 + col] = x;
    s += x; q = fmaf(x, x, q);
  }
  sS[t] = s; sQ[t] = q;
  __syncthreads();
  if (t < 128) {
    atomicAdd(ws + WS_SUM2 + t, sS[t] + sS[t+128] + sS[t+256] + sS[t+384]);
    atomicAdd(ws + WS_SQ2 + t, sQ[t] + sQ[t+128] + sQ[t+256] + sQ[t+384]);
  }
  // block 0: U = Wd @ Wn_bot, C0 = bd @ Wn_bot + bn_node (once for k_final)
  if (blockIdx.x == 0) {
    const int g = t >> 7;
    float u = 0.f, cc = 0.f;
#pragma unroll 8
    for (int e = g * 32; e < g * 32 + 32; ++e) {
      float wn = Wn[(size_t)(128 + e) * 128 + c0];
      u  = fmaf(Wd[e], wn, u);
      cc = fmaf(bd[e], wn, cc);
    }
    float* red = &sY[0][0];            // reuse as [8][128]
    red[g * 128 + c0] = u;
    red[512 + g * 128 + c0] = cc;
    __syncthreads();
    if (t < 128) {
      ws[WS_UV + t]  = red[t] + red[128 + t] + red[256 + t] + red[384 + t];
      ws[WS_C0V + t] = red[512 + t] + red[640 + t] + red[768 + t] +
                       red[896 + t] + bnn[t];
    }
  }
}

// ---- kC: BN2 -> out3 @ Wn_top + demand*U + C0 -> out ----------------------
// 500 blocks x 512 thr, 4 rows/block.
__global__ __launch_bounds__(512, 4) void k_final(const float* __restrict__ Wn,
                                                  const float* __restrict__ g2,
                                                  const float* __restrict__ bb2,
                                                  const float* __restrict__ dem,
                                                  float* __restrict__ out,
                                                  float* __restrict__ ws) {
  __shared__ float o3[4][132];
  __shared__ float sP[8][4][128];
  const int t = threadIdx.x;
  const int row0 = blockIdx.x * 4;
  const int c0 = t & 127;
  float m2 = ws[WS_SUM2 + c0] * 5e-4f;
  float v2 = ws[WS_SQ2 + c0] * 5e-4f - m2 * m2;
  float scv = g2[c0] * rsqrtf(v2 + BN_EPS);
  float shv = bb2[c0] - m2 * scv;
  {
    int r = t >> 7;
    o3[r][c0] = ws[WS_X2 + (size_t)(row0 + r) * 128 + c0] * scv + shv;
  }
  __syncthreads();
  // GEMM Wn_top: cg(32x4c) x seg(8x16k) x rh(2x2rows)
  {
    const int cg  = (t & 31) * 4;
    const int seg = (t >> 5) & 7;
    const int rh  = t >> 8;
    const int k0  = seg * 16;
    float acc[2][4] = {};
    float av[2][8];
#pragma unroll
    for (int kb = 0; kb < 16; kb += 8) {
      LD_AV2(o3[rh * 2], o3[rh * 2 + 1], k0 + kb, av);
      GB8_R2(Wn + cg, 128, k0 + kb, av, acc);
    }
#pragma unroll
    for (int r = 0; r < 2; ++r)
      *(float4*)&sP[seg][rh * 2 + r][cg] = *(float4*)acc[r];
  }
  __syncthreads();
  {
    int r = t >> 7;
    float x = ws[WS_C0V + c0] + dem[row0 + r] * ws[WS_UV + c0];
#pragma unroll
    for (int sg = 0; sg < 8; ++sg) x += sP[sg][r][c0];
    out[(size_t)(row0 + r) * 128 + c0] = x;
  }
}

extern "C" void kernel_launch(void* const* d_in, const int* in_sizes, int n_in,
                              void* d_out, int out_size, void* d_ws, size_t ws_size,
                              hipStream_t stream) {
  const float* cost   = (const float*)d_in[0];
  const float* dem    = (const float*)d_in[1];
  const float* rnd    = (const float*)d_in[2];
  // d_in[3] Wq, d_in[4] Wk unused (q == 0)
  const float* Wv     = (const float*)d_in[5];
  const float* mix1w  = (const float*)d_in[6];
  const float* mix1b  = (const float*)d_in[7];
  const float* mix2w  = (const float*)d_in[8];
  const float* mix2b  = (const float*)d_in[9];
  const float* Wo     = (const float*)d_in[10];
  const float* bo     = (const float*)d_in[11];
  const float* W1     = (const float*)d_in[12];
  const float* b1     = (const float*)d_in[13];
  const float* W2     = (const float*)d_in[14];
  const float* b2     = (const float*)d_in[15];
  const float* g1     = (const float*)d_in[16];
  const float* bb1    = (const float*)d_in[17];
  const float* g2     = (const float*)d_in[18];
  const float* bb2    = (const float*)d_in[19];
  const float* Wd     = (const float*)d_in[20];
  const float* bd     = (const float*)d_in[21];
  const float* Wn     = (const float*)d_in[22];
  const float* bnn    = (const float*)d_in[23];
  float* ws  = (float*)d_ws;
  float* out = (float*)d_out;

  // zero the 4x128 BN accumulators (2 KB)
  hipMemsetAsync(ws + WS_SUM1, 0, 512 * sizeof(float), stream);
  hipLaunchKernelGGL(k_attn,  dim3(500), dim3(512), 0, stream, cost, rnd, Wv,
                     mix1w, mix1b, mix2w, mix2b, Wo, bo, ws);
  hipLaunchKernelGGL(k_ffn,   dim3(250), dim3(512), 0, stream, W1, b1, g1, bb1,
                     W2, b2, Wn, Wd, bd, bnn, ws);
  hipLaunchKernelGGL(k_final, dim3(500), dim3(512), 0, stream, Wn, g2, bb2, dem,
                     out, ws);
}